// Round 11
// baseline (259.566 us; speedup 1.0000x reference)
//
#include <hip/hip_runtime.h>
#include <hip/hip_bf16.h>
#include <cstdint>

#define CIN   128
#define COUT  256
#define BATCH 16
#define HH    64
#define WW    64
#define TH    32
#define TW    32
#define NT    (BATCH*TH*TW)   /* 16384 winograd tiles */
#define APQ   (COUT*CIN)      /* U plane: 32768 elems */
#define BPQ   (NT*CIN)        /* V plane: 2097152 elems */

typedef __bf16 bf16x8 __attribute__((ext_vector_type(8)));
typedef float  f32x4  __attribute__((ext_vector_type(4)));

__device__ __forceinline__ void gload16(const void* g, void* l) {
    __builtin_amdgcn_global_load_lds(
        (const __attribute__((address_space(1))) uint32_t*)g,
        (__attribute__((address_space(3))) uint32_t*)l, 16, 0, 0);
}

// ---------------------------------------------------------------------------
// Kernel 1: weight transform  U[pq][k][c] = (G w G^T)[p][q], bf16
// ---------------------------------------------------------------------------
__global__ __launch_bounds__(256) void wg_wtrans(const float* __restrict__ w,
                                                 __hip_bfloat16* __restrict__ U) {
    int idx = blockIdx.x * 256 + threadIdx.x;       // idx = k*CIN + c
    if (idx >= COUT * CIN) return;
    const float* wp = w + idx * 9;
    float g[3][3];
#pragma unroll
    for (int x = 0; x < 3; x++)
#pragma unroll
        for (int y = 0; y < 3; y++) g[x][y] = wp[x * 3 + y];

    float t[4][3];
#pragma unroll
    for (int y = 0; y < 3; y++) {
        t[0][y] = g[0][y];
        t[1][y] = 0.5f * (g[0][y] + g[1][y] + g[2][y]);
        t[2][y] = 0.5f * (g[0][y] - g[1][y] + g[2][y]);
        t[3][y] = g[2][y];
    }
#pragma unroll
    for (int p = 0; p < 4; p++) {
        float u0 = t[p][0];
        float u1 = 0.5f * (t[p][0] + t[p][1] + t[p][2]);
        float u2 = 0.5f * (t[p][0] - t[p][1] + t[p][2]);
        float u3 = t[p][2];
        U[(p * 4 + 0) * APQ + idx] = __float2bfloat16(u0);
        U[(p * 4 + 1) * APQ + idx] = __float2bfloat16(u1);
        U[(p * 4 + 2) * APQ + idx] = __float2bfloat16(u2);
        U[(p * 4 + 3) * APQ + idx] = __float2bfloat16(u3);
    }
}

// ---------------------------------------------------------------------------
// Kernel 2: input transform  V[pq][bij][c] = (BT d BT^T)[p][q], bf16
// ---------------------------------------------------------------------------
__global__ __launch_bounds__(1024) void wg_itrans(const float* __restrict__ X,
                                                  __hip_bfloat16* __restrict__ V) {
    __shared__ float lds[32 * 265];
    const int c0 = blockIdx.x * 32;
    const int i  = blockIdx.y;
    const int b  = blockIdx.z;
    const int tid = threadIdx.x;

    for (int t = tid; t < 32 * 4; t += 1024) {
        int cc = t >> 2, r = t & 3;
        lds[cc * 265 + r * 66 + 0]  = 0.f;
        lds[cc * 265 + r * 66 + 65] = 0.f;
    }
    for (int t = tid; t < 32 * 4 * 64; t += 1024) {
        int x = t & 63, r = (t >> 6) & 3, cc = t >> 8;
        int y = 2 * i - 1 + r;
        float v = 0.f;
        if (y >= 0 && y < HH) v = X[(((b * CIN) + (c0 + cc)) * HH + y) * WW + x];
        lds[cc * 265 + r * 66 + 1 + x] = v;
    }
    __syncthreads();

    const int c = tid & 31;
    const int j = tid >> 5;
    const float* base = &lds[c * 265 + 2 * j];

    float t0[4], t1[4], t2[4], t3[4];
#pragma unroll
    for (int y = 0; y < 4; y++) {
        float a  = base[0 * 66 + y];
        float bb = base[1 * 66 + y];
        float cc = base[2 * 66 + y];
        float dd = base[3 * 66 + y];
        t0[y] = a - cc;
        t1[y] = bb + cc;
        t2[y] = cc - bb;
        t3[y] = bb - dd;
    }
    float vm[4][4];
#pragma unroll
    for (int p = 0; p < 4; p++) {
        const float* tp = (p == 0) ? t0 : (p == 1) ? t1 : (p == 2) ? t2 : t3;
        vm[p][0] = tp[0] - tp[2];
        vm[p][1] = tp[1] + tp[2];
        vm[p][2] = tp[2] - tp[1];
        vm[p][3] = tp[1] - tp[3];
    }

    const int bij = b * (TH * TW) + i * TW + j;
    const int vo  = bij * CIN + (c0 + c);
#pragma unroll
    for (int p = 0; p < 4; p++)
#pragma unroll
        for (int q = 0; q < 4; q++)
            V[(size_t)(p * 4 + q) * BPQ + vo] = __float2bfloat16(vm[p][q]);
}

// ---------------------------------------------------------------------------
// Kernel 3: fused GEMM + output transform — occupancy-first (2-3 blocks/CU).
// Block [128 kout x 64 bij], 256 thr = 4 waves (2m x 2n), wave tile 64x32.
// BK=32, 64 iters (pq = t>>2, ks = (t&3)*32).
// LDS: 4 bufs x 12KB (A 8KB + B 4KB) = 48KB -> 2-3 blocks resident/CU.
// Staging: contiguous granules, XOR slot swizzle s=(g^row^(row>>2))&3 on the
// SOURCE side; reads apply same XOR -> bijection onto contiguous 1KB/instr,
// conflict-free. Depth-2 prefetch, ONE barrier/iter (4-buf hazard analysis:
// buffer reuse separated by >= 2 barriers), steady vmcnt(6), tail 3 -> 0.
// Per-pq fold into 4 register Y-planes every 4th iter (before the wait).
// ~210 VGPR total: yac 128 + mac 32 + frags 24 + addressing.
// ---------------------------------------------------------------------------
#define BUFB 12288

__global__ __launch_bounds__(256, 3) void wg_gemm11(const __hip_bfloat16* __restrict__ U,
                                                    const __hip_bfloat16* __restrict__ V,
                                                    const float* __restrict__ bias,
                                                    float* __restrict__ out) {
    __shared__ char lds[4 * BUFB];       // 48 KB

    // bijective XCD swizzle (512 % 8 == 0): 64 consecutive wg per XCD
    int orig = blockIdx.x;
    int wgid = (orig & 7) * 64 + (orig >> 3);
    const int mt = wgid & 1, nt = wgid >> 1;
    const int m0 = mt * 128, n0 = nt * 64;

    const int tid  = threadIdx.x;
    const int lane = tid & 63;
    const int wave = tid >> 6;
    const int wm = wave >> 1, wn = wave & 1;
    const int la = lane & 15, hq = lane >> 4;

    // staging: A = 2 chunks/thread (c, c+256), B = 1 chunk (c). chunk c:
    // R = c>>2, slot s = c&3 holds granule g = s ^ (R&3) ^ ((R>>2)&3)
    const __hip_bfloat16 *paS0, *paS1, *pbS;
    int la0off, la1off, lboff;
    {
        int c1 = tid,       R1 = c1 >> 2, g1 = (c1 & 3) ^ (R1 & 3) ^ ((R1 >> 2) & 3);
        int c2 = tid + 256, R2 = c2 >> 2, g2 = (c2 & 3) ^ (R2 & 3) ^ ((R2 >> 2) & 3);
        paS0 = U + (m0 + R1) * CIN + g1 * 8;  la0off = c1 * 16;
        paS1 = U + (m0 + R2) * CIN + g2 * 8;  la1off = c2 * 16;
        pbS  = V + (size_t)(n0 + R1) * CIN + g1 * 8;  lboff = 8192 + c1 * 16;
    }

    // read offsets: row r, granule hq -> byte r*64 + (((hq^r^(r>>2))&3)<<4)
    // slot independent of wm/wn/mi/nj (all multiples of 4 in row / row>>2)
    const int slot  = (hq ^ la ^ (la >> 2)) & 3;
    const int abase = (wm * 64 + la) * 64 + slot * 16;          // + mi*1024
    const int bbase = 8192 + (wn * 32 + la) * 64 + slot * 16;   // + nj*1024

    f32x4 yac[2][2][4][2];
#pragma unroll
    for (int x = 0; x < 2; x++)
#pragma unroll
        for (int y = 0; y < 2; y++)
#pragma unroll
            for (int mi = 0; mi < 4; mi++)
#pragma unroll
                for (int nj = 0; nj < 2; nj++) yac[x][y][mi][nj] = (f32x4){0.f, 0.f, 0.f, 0.f};
    f32x4 mac[4][2];
    const f32x4 fz = (f32x4){0.f, 0.f, 0.f, 0.f};

    auto stage = [&](int t) {
        char* sb = lds + (t & 3) * BUFB;
        const int pq = t >> 2, ks = (t & 3) * 32;
        gload16(paS0 + (size_t)pq * APQ + ks, sb + la0off);
        gload16(paS1 + (size_t)pq * APQ + ks, sb + la1off);
        gload16(pbS  + (size_t)pq * BPQ + ks, sb + lboff);
    };

    auto fold = [&](int pq) {            // compile-time pq after full unroll
        const int p = pq >> 2, q = pq & 3;
        const float s1p = (p >= 2) ? -1.f : 1.f;
        const float s1q = (q >= 2) ? -1.f : 1.f;
        if (p != 3 && q != 3) {
#pragma unroll
            for (int mi = 0; mi < 4; mi++)
#pragma unroll
                for (int nj = 0; nj < 2; nj++) yac[0][0][mi][nj] += mac[mi][nj];
        }
        if (p != 3 && q != 0) {
#pragma unroll
            for (int mi = 0; mi < 4; mi++)
#pragma unroll
                for (int nj = 0; nj < 2; nj++) yac[0][1][mi][nj] += s1q * mac[mi][nj];
        }
        if (p != 0 && q != 3) {
#pragma unroll
            for (int mi = 0; mi < 4; mi++)
#pragma unroll
                for (int nj = 0; nj < 2; nj++) yac[1][0][mi][nj] += s1p * mac[mi][nj];
        }
        if (p != 0 && q != 0) {
            const float s11 = s1p * s1q;
#pragma unroll
            for (int mi = 0; mi < 4; mi++)
#pragma unroll
                for (int nj = 0; nj < 2; nj++) yac[1][1][mi][nj] += s11 * mac[mi][nj];
        }
    };

    // prologue: two stages in flight; body-0's vmcnt(6) waits stage 0 only
    stage(0);
    stage(1);

#pragma unroll
    for (int t = 0; t < 64; ++t) {
        if (t <= 61) stage(t + 2);
        if (t >= 4 && (t & 3) == 0) fold((t >> 2) - 1);

        if (t <= 61)      asm volatile("s_waitcnt vmcnt(6)");
        else if (t == 62) asm volatile("s_waitcnt vmcnt(3)");
        else              asm volatile("s_waitcnt vmcnt(0)");
        __builtin_amdgcn_s_barrier();
        __builtin_amdgcn_sched_barrier(0);

        const char* rb = lds + (t & 3) * BUFB;
        bf16x8 av0 = *reinterpret_cast<const bf16x8*>(rb + abase);
        bf16x8 av1 = *reinterpret_cast<const bf16x8*>(rb + abase + 1024);
        bf16x8 av2 = *reinterpret_cast<const bf16x8*>(rb + abase + 2048);
        bf16x8 av3 = *reinterpret_cast<const bf16x8*>(rb + abase + 3072);
        bf16x8 bv0 = *reinterpret_cast<const bf16x8*>(rb + bbase);
        bf16x8 bv1 = *reinterpret_cast<const bf16x8*>(rb + bbase + 1024);
        __builtin_amdgcn_sched_barrier(0);
        asm volatile("s_waitcnt lgkmcnt(0)");
        __builtin_amdgcn_sched_barrier(0);

        const bool init = (t & 3) == 0;
        __builtin_amdgcn_s_setprio(1);
        mac[0][0] = __builtin_amdgcn_mfma_f32_16x16x32_bf16(av0, bv0, init ? fz : mac[0][0], 0, 0, 0);
        mac[0][1] = __builtin_amdgcn_mfma_f32_16x16x32_bf16(av0, bv1, init ? fz : mac[0][1], 0, 0, 0);
        mac[1][0] = __builtin_amdgcn_mfma_f32_16x16x32_bf16(av1, bv0, init ? fz : mac[1][0], 0, 0, 0);
        mac[1][1] = __builtin_amdgcn_mfma_f32_16x16x32_bf16(av1, bv1, init ? fz : mac[1][1], 0, 0, 0);
        mac[2][0] = __builtin_amdgcn_mfma_f32_16x16x32_bf16(av2, bv0, init ? fz : mac[2][0], 0, 0, 0);
        mac[2][1] = __builtin_amdgcn_mfma_f32_16x16x32_bf16(av2, bv1, init ? fz : mac[2][1], 0, 0, 0);
        mac[3][0] = __builtin_amdgcn_mfma_f32_16x16x32_bf16(av3, bv0, init ? fz : mac[3][0], 0, 0, 0);
        mac[3][1] = __builtin_amdgcn_mfma_f32_16x16x32_bf16(av3, bv1, init ? fz : mac[3][1], 0, 0, 0);
        __builtin_amdgcn_s_setprio(0);
        __builtin_amdgcn_sched_barrier(0);
    }
    fold(15);

    // ---- writeout: D frag: col(bij)=lane&15, row(kout)=(lane>>4)*4+r ----
    const int lr = lane & 15, rg = lane >> 4;
#pragma unroll
    for (int mi = 0; mi < 4; mi++) {
#pragma unroll
        for (int r = 0; r < 4; r++) {
            const int kout = m0 + wm * 64 + mi * 16 + rg * 4 + r;
            const float bvv = bias[kout];
#pragma unroll
            for (int nj = 0; nj < 2; nj++) {
                const int bij = n0 + wn * 32 + nj * 16 + lr;
                const int bb = bij >> 10, ti = (bij >> 5) & 31, tj = bij & 31;
                float* op = out + (((size_t)bb * COUT + kout) * HH + 2 * ti) * WW + 2 * tj;
                *reinterpret_cast<float2*>(op) =
                    make_float2(yac[0][0][mi][nj][r] + bvv, yac[0][1][mi][nj][r] + bvv);
                *reinterpret_cast<float2*>(op + WW) =
                    make_float2(yac[1][0][mi][nj][r] + bvv, yac[1][1][mi][nj][r] + bvv);
            }
        }
    }
}

// ---------------------------------------------------------------------------
extern "C" void kernel_launch(void* const* d_in, const int* in_sizes, int n_in,
                              void* d_out, int out_size, void* d_ws, size_t ws_size,
                              hipStream_t stream) {
    const float* X    = (const float*)d_in[0];
    const float* w    = (const float*)d_in[1];
    const float* bias = (const float*)d_in[2];
    float* out        = (float*)d_out;

    __hip_bfloat16* U = (__hip_bfloat16*)d_ws;                       // 1 MB
    __hip_bfloat16* V = (__hip_bfloat16*)((char*)d_ws + (1u << 20)); // 64 MB

    wg_wtrans<<<(COUT * CIN + 255) / 256, 256, 0, stream>>>(w, U);
    wg_itrans<<<dim3(CIN / 32, TH, BATCH), 1024, 0, stream>>>(X, V);
    wg_gemm11<<<(COUT / 128) * (NT / 64), 256, 0, stream>>>(U, V, bias, out);
}

// Round 12
// 219.306 us; speedup vs baseline: 1.1836x; 1.1836x over previous
//
#include <hip/hip_runtime.h>
#include <hip/hip_bf16.h>
#include <cstdint>

#define CIN   128
#define COUT  256
#define BATCH 16
#define HH    64
#define WW    64
#define TH    32
#define TW    32
#define NT    (BATCH*TH*TW)   /* 16384 winograd tiles */
#define APQ   (COUT*CIN)      /* U plane: 32768 elems */
#define BPQ   (NT*CIN)        /* V plane: 2097152 elems */

typedef __bf16 bf16x8 __attribute__((ext_vector_type(8)));
typedef float  f32x4  __attribute__((ext_vector_type(4)));

__device__ __forceinline__ void gload16(const void* g, void* l) {
    __builtin_amdgcn_global_load_lds(
        (const __attribute__((address_space(1))) uint32_t*)g,
        (__attribute__((address_space(3))) uint32_t*)l, 16, 0, 0);
}

// ---------------------------------------------------------------------------
// Kernel 1: weight transform  U[pq][k][c] = (G w G^T)[p][q], bf16
// ---------------------------------------------------------------------------
__global__ __launch_bounds__(256) void wg_wtrans(const float* __restrict__ w,
                                                 __hip_bfloat16* __restrict__ U) {
    int idx = blockIdx.x * 256 + threadIdx.x;       // idx = k*CIN + c
    if (idx >= COUT * CIN) return;
    const float* wp = w + idx * 9;
    float g[3][3];
#pragma unroll
    for (int x = 0; x < 3; x++)
#pragma unroll
        for (int y = 0; y < 3; y++) g[x][y] = wp[x * 3 + y];

    float t[4][3];
#pragma unroll
    for (int y = 0; y < 3; y++) {
        t[0][y] = g[0][y];
        t[1][y] = 0.5f * (g[0][y] + g[1][y] + g[2][y]);
        t[2][y] = 0.5f * (g[0][y] - g[1][y] + g[2][y]);
        t[3][y] = g[2][y];
    }
#pragma unroll
    for (int p = 0; p < 4; p++) {
        float u0 = t[p][0];
        float u1 = 0.5f * (t[p][0] + t[p][1] + t[p][2]);
        float u2 = 0.5f * (t[p][0] - t[p][1] + t[p][2]);
        float u3 = t[p][2];
        U[(p * 4 + 0) * APQ + idx] = __float2bfloat16(u0);
        U[(p * 4 + 1) * APQ + idx] = __float2bfloat16(u1);
        U[(p * 4 + 2) * APQ + idx] = __float2bfloat16(u2);
        U[(p * 4 + 3) * APQ + idx] = __float2bfloat16(u3);
    }
}

// ---------------------------------------------------------------------------
// Kernel 2: input transform  V[pq][bij][c] = (BT d BT^T)[p][q], bf16
// ---------------------------------------------------------------------------
__global__ __launch_bounds__(1024) void wg_itrans(const float* __restrict__ X,
                                                  __hip_bfloat16* __restrict__ V) {
    __shared__ float lds[32 * 265];
    const int c0 = blockIdx.x * 32;
    const int i  = blockIdx.y;
    const int b  = blockIdx.z;
    const int tid = threadIdx.x;

    for (int t = tid; t < 32 * 4; t += 1024) {
        int cc = t >> 2, r = t & 3;
        lds[cc * 265 + r * 66 + 0]  = 0.f;
        lds[cc * 265 + r * 66 + 65] = 0.f;
    }
    for (int t = tid; t < 32 * 4 * 64; t += 1024) {
        int x = t & 63, r = (t >> 6) & 3, cc = t >> 8;
        int y = 2 * i - 1 + r;
        float v = 0.f;
        if (y >= 0 && y < HH) v = X[(((b * CIN) + (c0 + cc)) * HH + y) * WW + x];
        lds[cc * 265 + r * 66 + 1 + x] = v;
    }
    __syncthreads();

    const int c = tid & 31;
    const int j = tid >> 5;
    const float* base = &lds[c * 265 + 2 * j];

    float t0[4], t1[4], t2[4], t3[4];
#pragma unroll
    for (int y = 0; y < 4; y++) {
        float a  = base[0 * 66 + y];
        float bb = base[1 * 66 + y];
        float cc = base[2 * 66 + y];
        float dd = base[3 * 66 + y];
        t0[y] = a - cc;
        t1[y] = bb + cc;
        t2[y] = cc - bb;
        t3[y] = bb - dd;
    }
    float vm[4][4];
#pragma unroll
    for (int p = 0; p < 4; p++) {
        const float* tp = (p == 0) ? t0 : (p == 1) ? t1 : (p == 2) ? t2 : t3;
        vm[p][0] = tp[0] - tp[2];
        vm[p][1] = tp[1] + tp[2];
        vm[p][2] = tp[2] - tp[1];
        vm[p][3] = tp[1] - tp[3];
    }

    const int bij = b * (TH * TW) + i * TW + j;
    const int vo  = bij * CIN + (c0 + c);
#pragma unroll
    for (int p = 0; p < 4; p++)
#pragma unroll
        for (int q = 0; q < 4; q++)
            V[(size_t)(p * 4 + q) * BPQ + vo] = __float2bfloat16(vm[p][q]);
}

// ---------------------------------------------------------------------------
// Kernel 3: fused GEMM + output transform — occupancy-first, small wave tile.
// Block [64 kout x 64 bij], 256 thr = 4 waves (2m x 2n), wave tile 32x32.
// Registers/wave ~115 (yac 64 + mac 16 + frags 16 + addr) -> 4 waves/SIMD.
// LDS: 4 bufs x 8KB (A 4KB + B 4KB) = 32KB -> 4 blocks/CU (grid 1024 = 4/CU).
// BK=32, 64 iters (pq = t>>2, ks = (t&3)*32). Depth-3 staging issued
// POST-barrier (race-free: all waves' prior reads drained via their own
// lgkmcnt(0) before arriving). Counted vmcnt(4) BEFORE the barrier (barrier
// publishes all waves' stage-t). XOR granule swizzle g = s^(R&3)^((R>>2)&3):
// source-side permutation within each row's 64B (coalescing kept, 16 lines
// per gload16), reads 2 lanes/bank-quad = free (m136).
// Per-pq fold into 4 register Y-planes every 4 iters (compile-time weights).
// ---------------------------------------------------------------------------
#define BUFB 8192

__global__ __launch_bounds__(256, 4) void wg_gemm12(const __hip_bfloat16* __restrict__ U,
                                                    const __hip_bfloat16* __restrict__ V,
                                                    const float* __restrict__ bias,
                                                    float* __restrict__ out) {
    __shared__ char lds[4 * BUFB];       // 32 KB

    // bijective XCD swizzle (1024 % 8 == 0): 128 consecutive wg per XCD;
    // 4 consecutive wgid share nt (same B-panel -> XCD L2 locality)
    int orig = blockIdx.x;
    int wgid = (orig & 7) * 128 + (orig >> 3);
    const int mt = wgid & 3, nt = wgid >> 2;
    const int m0 = mt * 64, n0 = nt * 64;

    const int tid  = threadIdx.x;
    const int lane = tid & 63;
    const int wave = tid >> 6;
    const int wm = wave >> 1, wn = wave & 1;
    const int la = lane & 15, hq = lane >> 4;

    // staging: chunk c = tid (A) and tid (B): R = c>>2, slot s = c&3 holds
    // granule g = s ^ (R&3) ^ ((R>>2)&3)   (bijective per row)
    const __hip_bfloat16 *paS, *pbS;
    int laoff, lboff;
    {
        int c = tid, R = c >> 2;
        int g = (c & 3) ^ (R & 3) ^ ((R >> 2) & 3);
        paS = U + (m0 + R) * CIN + g * 8;  laoff = c * 16;
        pbS = V + (size_t)(n0 + R) * CIN + g * 8;  lboff = 4096 + c * 16;
    }

    // read offsets: row r, k-granule hq -> byte r*64 + ((hq^(r&3)^((r>>2)&3))<<4)
    // row = w*32 + mi*16 + la: (r&3)=(la&3), ((r>>2)&3)=((la>>2)&3) -> uniform
    const int slot  = (hq ^ (la & 3) ^ ((la >> 2) & 3)) & 3;
    const int abase = (wm * 32 + la) * 64 + slot * 16;           // + mi*1024
    const int bbase = 4096 + (wn * 32 + la) * 64 + slot * 16;    // + nj*1024

    f32x4 yac[2][2][2][2];               // [x][y][mi][nj] = 64 regs
#pragma unroll
    for (int x = 0; x < 2; x++)
#pragma unroll
        for (int y = 0; y < 2; y++)
#pragma unroll
            for (int mi = 0; mi < 2; mi++)
#pragma unroll
                for (int nj = 0; nj < 2; nj++) yac[x][y][mi][nj] = (f32x4){0.f, 0.f, 0.f, 0.f};
    f32x4 mac[2][2];                     // 16 regs
    const f32x4 fz = (f32x4){0.f, 0.f, 0.f, 0.f};

    auto stage = [&](int t) {
        char* sb = lds + (t & 3) * BUFB;
        const int pq = t >> 2, ks = (t & 3) * 32;
        gload16(paS + (size_t)pq * APQ + ks, sb + laoff);
        gload16(pbS + (size_t)pq * BPQ + ks, sb + lboff);
    };

    auto fold = [&](int pq) {            // compile-time pq after full unroll
        const int p = pq >> 2, q = pq & 3;
        const float s1p = (p >= 2) ? -1.f : 1.f;
        const float s1q = (q >= 2) ? -1.f : 1.f;
        if (p != 3 && q != 3) {
#pragma unroll
            for (int mi = 0; mi < 2; mi++)
#pragma unroll
                for (int nj = 0; nj < 2; nj++) yac[0][0][mi][nj] += mac[mi][nj];
        }
        if (p != 3 && q != 0) {
#pragma unroll
            for (int mi = 0; mi < 2; mi++)
#pragma unroll
                for (int nj = 0; nj < 2; nj++) yac[0][1][mi][nj] += s1q * mac[mi][nj];
        }
        if (p != 0 && q != 3) {
#pragma unroll
            for (int mi = 0; mi < 2; mi++)
#pragma unroll
                for (int nj = 0; nj < 2; nj++) yac[1][0][mi][nj] += s1p * mac[mi][nj];
        }
        if (p != 0 && q != 0) {
            const float s11 = s1p * s1q;
#pragma unroll
            for (int mi = 0; mi < 2; mi++)
#pragma unroll
                for (int nj = 0; nj < 2; nj++) yac[1][1][mi][nj] += s11 * mac[mi][nj];
        }
    };

    // prologue: 3 stages in flight (6 loads/wave outstanding)
    stage(0); stage(1); stage(2);

#pragma unroll
    for (int t = 0; t < 64; ++t) {
        if (t >= 4 && (t & 3) == 0) fold((t >> 2) - 1);

        // counted drain BEFORE barrier: ensures THIS wave's stage-t landed;
        // barrier then publishes all waves' stage-t.
        if (t <= 61)      asm volatile("s_waitcnt vmcnt(4)");
        else if (t == 62) asm volatile("s_waitcnt vmcnt(2)");
        else              asm volatile("s_waitcnt vmcnt(0)");
        __builtin_amdgcn_s_barrier();
        __builtin_amdgcn_sched_barrier(0);

        if (t <= 60) stage(t + 3);       // post-barrier: race-free (readers
                                         // of this buf drained pre-barrier)

        const char* rb = lds + (t & 3) * BUFB;
        bf16x8 av0 = *reinterpret_cast<const bf16x8*>(rb + abase);
        bf16x8 av1 = *reinterpret_cast<const bf16x8*>(rb + abase + 1024);
        bf16x8 bv0 = *reinterpret_cast<const bf16x8*>(rb + bbase);
        bf16x8 bv1 = *reinterpret_cast<const bf16x8*>(rb + bbase + 1024);
        __builtin_amdgcn_sched_barrier(0);
        asm volatile("s_waitcnt lgkmcnt(0)");
        __builtin_amdgcn_sched_barrier(0);

        const bool init = (t & 3) == 0;
        __builtin_amdgcn_s_setprio(1);
        mac[0][0] = __builtin_amdgcn_mfma_f32_16x16x32_bf16(av0, bv0, init ? fz : mac[0][0], 0, 0, 0);
        mac[0][1] = __builtin_amdgcn_mfma_f32_16x16x32_bf16(av0, bv1, init ? fz : mac[0][1], 0, 0, 0);
        mac[1][0] = __builtin_amdgcn_mfma_f32_16x16x32_bf16(av1, bv0, init ? fz : mac[1][0], 0, 0, 0);
        mac[1][1] = __builtin_amdgcn_mfma_f32_16x16x32_bf16(av1, bv1, init ? fz : mac[1][1], 0, 0, 0);
        __builtin_amdgcn_s_setprio(0);
        __builtin_amdgcn_sched_barrier(0);
    }
    fold(15);

    // ---- writeout: D frag: col(bij)=lane&15, row(kout)=(lane>>4)*4+r ----
    const int lr = lane & 15, rg = lane >> 4;
#pragma unroll
    for (int mi = 0; mi < 2; mi++) {
#pragma unroll
        for (int r = 0; r < 4; r++) {
            const int kout = m0 + wm * 32 + mi * 16 + rg * 4 + r;
            const float bvv = bias[kout];
#pragma unroll
            for (int nj = 0; nj < 2; nj++) {
                const int bij = n0 + wn * 32 + nj * 16 + lr;
                const int bb = bij >> 10, ti = (bij >> 5) & 31, tj = bij & 31;
                float* op = out + (((size_t)bb * COUT + kout) * HH + 2 * ti) * WW + 2 * tj;
                *reinterpret_cast<float2*>(op) =
                    make_float2(yac[0][0][mi][nj][r] + bvv, yac[0][1][mi][nj][r] + bvv);
                *reinterpret_cast<float2*>(op + WW) =
                    make_float2(yac[1][0][mi][nj][r] + bvv, yac[1][1][mi][nj][r] + bvv);
            }
        }
    }
}

// ---------------------------------------------------------------------------
extern "C" void kernel_launch(void* const* d_in, const int* in_sizes, int n_in,
                              void* d_out, int out_size, void* d_ws, size_t ws_size,
                              hipStream_t stream) {
    const float* X    = (const float*)d_in[0];
    const float* w    = (const float*)d_in[1];
    const float* bias = (const float*)d_in[2];
    float* out        = (float*)d_out;

    __hip_bfloat16* U = (__hip_bfloat16*)d_ws;                       // 1 MB
    __hip_bfloat16* V = (__hip_bfloat16*)((char*)d_ws + (1u << 20)); // 64 MB

    wg_wtrans<<<(COUT * CIN + 255) / 256, 256, 0, stream>>>(w, U);
    wg_itrans<<<dim3(CIN / 32, TH, BATCH), 1024, 0, stream>>>(X, V);
    wg_gemm12<<<(COUT / 64) * (NT / 64), 256, 0, stream>>>(U, V, bias, out);
}

// Round 13
// 68.625 us; speedup vs baseline: 3.7824x; 3.1957x over previous
//
#include <hip/hip_runtime.h>
#include <hip/hip_bf16.h>
#include <cstdint>

#define CIN   128
#define COUT  256
#define BATCH 16
#define HH    64
#define WW    64
#define TH    32
#define TW    32
#define NT    (BATCH*TH*TW)   /* 16384 winograd tiles */
#define APQ   (COUT*CIN)      /* U plane: 32768 elems */
#define BPQ   (NT*CIN)        /* V plane: 2097152 elems */

typedef __bf16 bf16x8 __attribute__((ext_vector_type(8)));
typedef float  f32x4  __attribute__((ext_vector_type(4)));

__device__ __forceinline__ void gload16(const void* g, void* l) {
    __builtin_amdgcn_global_load_lds(
        (const __attribute__((address_space(1))) uint32_t*)g,
        (__attribute__((address_space(3))) uint32_t*)l, 16, 0, 0);
}

// ---------------------------------------------------------------------------
// Kernel 1: weight transform  U[pq][k][c] = (G w G^T)[p][q], bf16
// ---------------------------------------------------------------------------
__global__ __launch_bounds__(256) void wg_wtrans(const float* __restrict__ w,
                                                 __hip_bfloat16* __restrict__ U) {
    int idx = blockIdx.x * 256 + threadIdx.x;       // idx = k*CIN + c
    if (idx >= COUT * CIN) return;
    const float* wp = w + idx * 9;
    float g[3][3];
#pragma unroll
    for (int x = 0; x < 3; x++)
#pragma unroll
        for (int y = 0; y < 3; y++) g[x][y] = wp[x * 3 + y];

    float t[4][3];
#pragma unroll
    for (int y = 0; y < 3; y++) {
        t[0][y] = g[0][y];
        t[1][y] = 0.5f * (g[0][y] + g[1][y] + g[2][y]);
        t[2][y] = 0.5f * (g[0][y] - g[1][y] + g[2][y]);
        t[3][y] = g[2][y];
    }
#pragma unroll
    for (int p = 0; p < 4; p++) {
        float u0 = t[p][0];
        float u1 = 0.5f * (t[p][0] + t[p][1] + t[p][2]);
        float u2 = 0.5f * (t[p][0] - t[p][1] + t[p][2]);
        float u3 = t[p][2];
        U[(p * 4 + 0) * APQ + idx] = __float2bfloat16(u0);
        U[(p * 4 + 1) * APQ + idx] = __float2bfloat16(u1);
        U[(p * 4 + 2) * APQ + idx] = __float2bfloat16(u2);
        U[(p * 4 + 3) * APQ + idx] = __float2bfloat16(u3);
    }
}

// ---------------------------------------------------------------------------
// Kernel 2: input transform  V[pq][bij][c] = (BT d BT^T)[p][q], bf16
// ---------------------------------------------------------------------------
__global__ __launch_bounds__(1024) void wg_itrans(const float* __restrict__ X,
                                                  __hip_bfloat16* __restrict__ V) {
    __shared__ float lds[32 * 265];
    const int c0 = blockIdx.x * 32;
    const int i  = blockIdx.y;
    const int b  = blockIdx.z;
    const int tid = threadIdx.x;

    for (int t = tid; t < 32 * 4; t += 1024) {
        int cc = t >> 2, r = t & 3;
        lds[cc * 265 + r * 66 + 0]  = 0.f;
        lds[cc * 265 + r * 66 + 65] = 0.f;
    }
    for (int t = tid; t < 32 * 4 * 64; t += 1024) {
        int x = t & 63, r = (t >> 6) & 3, cc = t >> 8;
        int y = 2 * i - 1 + r;
        float v = 0.f;
        if (y >= 0 && y < HH) v = X[(((b * CIN) + (c0 + cc)) * HH + y) * WW + x];
        lds[cc * 265 + r * 66 + 1 + x] = v;
    }
    __syncthreads();

    const int c = tid & 31;
    const int j = tid >> 5;
    const float* base = &lds[c * 265 + 2 * j];

    float t0[4], t1[4], t2[4], t3[4];
#pragma unroll
    for (int y = 0; y < 4; y++) {
        float a  = base[0 * 66 + y];
        float bb = base[1 * 66 + y];
        float cc = base[2 * 66 + y];
        float dd = base[3 * 66 + y];
        t0[y] = a - cc;
        t1[y] = bb + cc;
        t2[y] = cc - bb;
        t3[y] = bb - dd;
    }
    float vm[4][4];
#pragma unroll
    for (int p = 0; p < 4; p++) {
        const float* tp = (p == 0) ? t0 : (p == 1) ? t1 : (p == 2) ? t2 : t3;
        vm[p][0] = tp[0] - tp[2];
        vm[p][1] = tp[1] + tp[2];
        vm[p][2] = tp[2] - tp[1];
        vm[p][3] = tp[1] - tp[3];
    }

    const int bij = b * (TH * TW) + i * TW + j;
    const int vo  = bij * CIN + (c0 + c);
#pragma unroll
    for (int p = 0; p < 4; p++)
#pragma unroll
        for (int q = 0; q < 4; q++)
            V[(size_t)(p * 4 + q) * BPQ + vo] = __float2bfloat16(vm[p][q]);
}

// ---------------------------------------------------------------------------
// Kernel 3: fused GEMM + output transform — merged slot, STATIC reg sets.
// Block [128 kout x 128 bij], 512 thr = 8 waves (2m x 4n), wave tile 64x32.
// GRID FIX vs R9: n0 = nt*128 (non-overlapping), grid = 2 x NT/128 = 256
// blocks = exactly 1/CU. (R9 launched this 128-wide tile on a 64-spaced
// grid -> every output computed twice.)
// One slot per BK=64 (32 slots): 16 MFMA + 12 ds_read between ONE barrier
// pair. kk0 fragments in named double-buffer sets aX/bX <-> aY/bY; kk1 set
// a1/b1 read at slot top. Counted lgkmcnt(6); counted vmcnt(8); 4 LDS
// buffers, depth-3 staging. Fold = wave-uniform branches.
// ---------------------------------------------------------------------------
#define ABYTES 16384
#define BUFSZ  32768

__global__ __launch_bounds__(512, 2) void wg_gemm13(const __hip_bfloat16* __restrict__ U,
                                                    const __hip_bfloat16* __restrict__ V,
                                                    const float* __restrict__ bias,
                                                    float* __restrict__ out) {
    __shared__ char lds[4 * BUFSZ];      // 128 KB

    // bijective XCD swizzle (256 % 8 == 0): 32 consecutive wg per XCD
    int orig = blockIdx.x;
    int wgid = (orig & 7) * 32 + (orig >> 3);
    const int mt = wgid & 1, nt = wgid >> 1;
    const int m0 = mt * 128, n0 = nt * 128;

    const int tid  = threadIdx.x;
    const int lane = tid & 63;
    const int wave = tid >> 6;
    const int wm = wave >> 2, wn = wave & 3;

    // staging: chunk c holds tile granule (row R=c>>3, gran G=(c&7)^(R&7))
    const __hip_bfloat16* pa[2];
    const __hip_bfloat16* pb[2];
    int ldsA[2], ldsB[2];
#pragma unroll
    for (int ch = 0; ch < 2; ch++) {
        int c = ch * 512 + tid;
        int R = c >> 3;
        int G = (c & 7) ^ (R & 7);
        pa[ch] = U + (m0 + R) * CIN + G * 8;
        pb[ch] = V + (size_t)(n0 + R) * CIN + G * 8;
        ldsA[ch] = c * 16;
        ldsB[ch] = ABYTES + c * 16;
    }

    // ds_read offsets: row r, k-granule g -> byte r*128 + ((g ^ (r&7))<<4)
    const int la = lane & 15, hq = lane >> 4, l7 = lane & 7;
    int aoff[2], boff[2];
#pragma unroll
    for (int kk = 0; kk < 2; kk++) {
        int g = (kk * 4 + hq) ^ l7;
        aoff[kk] = (wm * 64 + la) * 128 + (g << 4);
        boff[kk] = ABYTES + (wn * 32 + la) * 128 + (g << 4);
    }

    f32x4 yac[2][2][4][2];
#pragma unroll
    for (int x = 0; x < 2; x++)
#pragma unroll
        for (int y = 0; y < 2; y++)
#pragma unroll
            for (int mi = 0; mi < 4; mi++)
#pragma unroll
                for (int nj = 0; nj < 2; nj++) yac[x][y][mi][nj] = (f32x4){0.f, 0.f, 0.f, 0.f};
    f32x4 mac[4][2];
    const f32x4 fz = (f32x4){0.f, 0.f, 0.f, 0.f};

    bf16x8 aX[4], bX[2], aY[4], bY[2];   // kk0 double-buffer (named sets)
    bf16x8 a1[4], b1[2];                 // kk1 per-slot set

    auto stage = [&](int s) {
        char* sb = lds + (s & 3) * BUFSZ;
        const int pq = s >> 1, kb = (s & 1) * 64;
        gload16(pa[0] + pq * APQ + kb, sb + ldsA[0]);
        gload16(pa[1] + pq * APQ + kb, sb + ldsA[1]);
        gload16(pb[0] + (size_t)pq * BPQ + kb, sb + ldsB[0]);
        gload16(pb[1] + (size_t)pq * BPQ + kb, sb + ldsB[1]);
    };

    auto fold = [&](int pq) {            // M[pq] -> Y planes, uniform branches
        const int p = pq >> 2, q = pq & 3;
        const float s1p = (p >= 2) ? -1.f : 1.f;
        const float s1q = (q >= 2) ? -1.f : 1.f;
        if (p != 3 && q != 3) {
#pragma unroll
            for (int mi = 0; mi < 4; mi++)
#pragma unroll
                for (int nj = 0; nj < 2; nj++) yac[0][0][mi][nj] += mac[mi][nj];
        }
        if (p != 3 && q != 0) {
#pragma unroll
            for (int mi = 0; mi < 4; mi++)
#pragma unroll
                for (int nj = 0; nj < 2; nj++) yac[0][1][mi][nj] += s1q * mac[mi][nj];
        }
        if (p != 0 && q != 3) {
#pragma unroll
            for (int mi = 0; mi < 4; mi++)
#pragma unroll
                for (int nj = 0; nj < 2; nj++) yac[1][0][mi][nj] += s1p * mac[mi][nj];
        }
        if (p != 0 && q != 0) {
            const float s11 = s1p * s1q;
#pragma unroll
            for (int mi = 0; mi < 4; mi++)
#pragma unroll
                for (int nj = 0; nj < 2; nj++) yac[1][1][mi][nj] += s11 * mac[mi][nj];
        }
    };

#define SLOT(T, AIN, BIN, AOUT, BOUT, VMC, STG, PRE, INIT, LGK2)              \
    {                                                                          \
        const int t_ = (T);                                                    \
        if (STG) stage(t_ + 3);                                                \
        if ((VMC) == 8)      asm volatile("s_waitcnt vmcnt(8)");               \
        else if ((VMC) == 4) asm volatile("s_waitcnt vmcnt(4)");               \
        else if ((VMC) == 0) asm volatile("s_waitcnt vmcnt(0)");               \
        __builtin_amdgcn_s_barrier();                                          \
        __builtin_amdgcn_sched_barrier(0);                                     \
        {                                                                      \
            const char* rb_ = lds + (t_ & 3) * BUFSZ;                          \
            _Pragma("unroll")                                                  \
            for (int mi = 0; mi < 4; mi++)                                     \
                a1[mi] = *reinterpret_cast<const bf16x8*>(rb_ + aoff[1] + mi * 2048); \
            _Pragma("unroll")                                                  \
            for (int nj = 0; nj < 2; nj++)                                     \
                b1[nj] = *reinterpret_cast<const bf16x8*>(rb_ + boff[1] + nj * 2048); \
        }                                                                      \
        __builtin_amdgcn_sched_barrier(0);                                     \
        asm volatile("s_waitcnt lgkmcnt(6)");                                  \
        __builtin_amdgcn_sched_barrier(0);                                     \
        __builtin_amdgcn_s_setprio(1);                                         \
        _Pragma("unroll")                                                      \
        for (int mi = 0; mi < 4; mi++)                                         \
            _Pragma("unroll")                                                  \
            for (int nj = 0; nj < 2; nj++)                                     \
                mac[mi][nj] = __builtin_amdgcn_mfma_f32_16x16x32_bf16(         \
                    AIN[mi], BIN[nj], (INIT) ? fz : mac[mi][nj], 0, 0, 0);     \
        __builtin_amdgcn_s_setprio(0);                                         \
        if (PRE) {                                                             \
            const char* rb2_ = lds + ((t_ + 1) & 3) * BUFSZ;                   \
            _Pragma("unroll")                                                  \
            for (int mi = 0; mi < 4; mi++)                                     \
                AOUT[mi] = *reinterpret_cast<const bf16x8*>(rb2_ + aoff[0] + mi * 2048); \
            _Pragma("unroll")                                                  \
            for (int nj = 0; nj < 2; nj++)                                     \
                BOUT[nj] = *reinterpret_cast<const bf16x8*>(rb2_ + boff[0] + nj * 2048); \
        }                                                                      \
        __builtin_amdgcn_sched_barrier(0);                                     \
        if ((LGK2) == 6) asm volatile("s_waitcnt lgkmcnt(6)");                 \
        else             asm volatile("s_waitcnt lgkmcnt(0)");                 \
        __builtin_amdgcn_sched_barrier(0);                                     \
        __builtin_amdgcn_s_setprio(1);                                         \
        _Pragma("unroll")                                                      \
        for (int mi = 0; mi < 4; mi++)                                         \
            _Pragma("unroll")                                                  \
            for (int nj = 0; nj < 2; nj++)                                     \
                mac[mi][nj] = __builtin_amdgcn_mfma_f32_16x16x32_bf16(         \
                    a1[mi], b1[nj], mac[mi][nj], 0, 0, 0);                     \
        __builtin_amdgcn_s_setprio(0);                                         \
        __builtin_amdgcn_sched_barrier(0);                                     \
        __builtin_amdgcn_s_barrier();                                          \
    }

    // prologue: 3 stages in flight; kk0 regs for slot 0 -> set X
    stage(0); stage(1); stage(2);
    asm volatile("s_waitcnt vmcnt(8)");  // stage 0 complete
    __builtin_amdgcn_s_barrier();
    {
        const char* rb_ = lds;
#pragma unroll
        for (int mi = 0; mi < 4; mi++)
            aX[mi] = *reinterpret_cast<const bf16x8*>(rb_ + aoff[0] + mi * 2048);
#pragma unroll
        for (int nj = 0; nj < 2; nj++)
            bX[nj] = *reinterpret_cast<const bf16x8*>(rb_ + boff[0] + nj * 2048);
    }

    for (int tt = 0; tt < 28; tt += 2) {
        if (tt >= 2) fold((tt >> 1) - 1);
        SLOT(tt,     aX, bX, aY, bY, 8, true, true, true,  6)
        SLOT(tt + 1, aY, bY, aX, bX, 8, true, true, false, 6)
    }
    fold(13);
    SLOT(28, aX, bX, aY, bY, 8,  true,  true,  true,  6)
    SLOT(29, aY, bY, aX, bX, 4,  false, true,  false, 6)
    fold(14);
    SLOT(30, aX, bX, aY, bY, 0,  false, true,  true,  6)
    SLOT(31, aY, bY, aX, bX, -1, false, false, false, 0)
    fold(15);

#undef SLOT

    // ---- writeout: D frag: col(bij)=lane&15, row(kout)=(lane>>4)*4+r ----
    const int lr = lane & 15, rg = lane >> 4;
#pragma unroll
    for (int mi = 0; mi < 4; mi++) {
#pragma unroll
        for (int r = 0; r < 4; r++) {
            const int kout = m0 + wm * 64 + mi * 16 + rg * 4 + r;
            const float bvv = bias[kout];
#pragma unroll
            for (int nj = 0; nj < 2; nj++) {
                const int bij = n0 + wn * 32 + nj * 16 + lr;
                const int bb = bij >> 10, ti = (bij >> 5) & 31, tj = bij & 31;
                float* op = out + (((size_t)bb * COUT + kout) * HH + 2 * ti) * WW + 2 * tj;
                *reinterpret_cast<float2*>(op) =
                    make_float2(yac[0][0][mi][nj][r] + bvv, yac[0][1][mi][nj][r] + bvv);
                *reinterpret_cast<float2*>(op + WW) =
                    make_float2(yac[1][0][mi][nj][r] + bvv, yac[1][1][mi][nj][r] + bvv);
            }
        }
    }
}

// ---------------------------------------------------------------------------
extern "C" void kernel_launch(void* const* d_in, const int* in_sizes, int n_in,
                              void* d_out, int out_size, void* d_ws, size_t ws_size,
                              hipStream_t stream) {
    const float* X    = (const float*)d_in[0];
    const float* w    = (const float*)d_in[1];
    const float* bias = (const float*)d_in[2];
    float* out        = (float*)d_out;

    __hip_bfloat16* U = (__hip_bfloat16*)d_ws;                       // 1 MB
    __hip_bfloat16* V = (__hip_bfloat16*)((char*)d_ws + (1u << 20)); // 64 MB

    wg_wtrans<<<(COUT * CIN + 255) / 256, 256, 0, stream>>>(w, U);
    wg_itrans<<<dim3(CIN / 32, TH, BATCH), 1024, 0, stream>>>(X, V);
    wg_gemm13<<<(COUT / 128) * (NT / 128), 512, 0, stream>>>(U, V, bias, out);
}

// Round 14
// 67.781 us; speedup vs baseline: 3.8295x; 1.0124x over previous
//
#include <hip/hip_runtime.h>
#include <hip/hip_bf16.h>
#include <cstdint>

#define CIN   128
#define COUT  256
#define BATCH 16
#define HH    64
#define WW    64
#define TH    32
#define TW    32
#define NT    (BATCH*TH*TW)   /* 16384 winograd tiles */
#define APQ   (COUT*CIN)      /* U plane: 32768 elems */
#define BPQ   (NT*CIN)        /* V plane: 2097152 elems */

typedef __bf16 bf16x8 __attribute__((ext_vector_type(8)));
typedef float  f32x4  __attribute__((ext_vector_type(4)));

__device__ __forceinline__ void gload16(const void* g, void* l) {
    __builtin_amdgcn_global_load_lds(
        (const __attribute__((address_space(1))) uint32_t*)g,
        (__attribute__((address_space(3))) uint32_t*)l, 16, 0, 0);
}

// ---------------------------------------------------------------------------
// Kernel 1: weight transform  U[pq][k][c] = (G w G^T)[p][q], bf16
// ---------------------------------------------------------------------------
__global__ __launch_bounds__(256) void wg_wtrans(const float* __restrict__ w,
                                                 __hip_bfloat16* __restrict__ U) {
    int idx = blockIdx.x * 256 + threadIdx.x;       // idx = k*CIN + c
    if (idx >= COUT * CIN) return;
    const float* wp = w + idx * 9;
    float g[3][3];
#pragma unroll
    for (int x = 0; x < 3; x++)
#pragma unroll
        for (int y = 0; y < 3; y++) g[x][y] = wp[x * 3 + y];

    float t[4][3];
#pragma unroll
    for (int y = 0; y < 3; y++) {
        t[0][y] = g[0][y];
        t[1][y] = 0.5f * (g[0][y] + g[1][y] + g[2][y]);
        t[2][y] = 0.5f * (g[0][y] - g[1][y] + g[2][y]);
        t[3][y] = g[2][y];
    }
#pragma unroll
    for (int p = 0; p < 4; p++) {
        float u0 = t[p][0];
        float u1 = 0.5f * (t[p][0] + t[p][1] + t[p][2]);
        float u2 = 0.5f * (t[p][0] - t[p][1] + t[p][2]);
        float u3 = t[p][2];
        U[(p * 4 + 0) * APQ + idx] = __float2bfloat16(u0);
        U[(p * 4 + 1) * APQ + idx] = __float2bfloat16(u1);
        U[(p * 4 + 2) * APQ + idx] = __float2bfloat16(u2);
        U[(p * 4 + 3) * APQ + idx] = __float2bfloat16(u3);
    }
}

// ---------------------------------------------------------------------------
// Kernel 2: input transform  V[pq][bij][c] = (BT d BT^T)[p][q], bf16
// ---------------------------------------------------------------------------
__global__ __launch_bounds__(1024) void wg_itrans(const float* __restrict__ X,
                                                  __hip_bfloat16* __restrict__ V) {
    __shared__ float lds[32 * 265];
    const int c0 = blockIdx.x * 32;
    const int i  = blockIdx.y;
    const int b  = blockIdx.z;
    const int tid = threadIdx.x;

    for (int t = tid; t < 32 * 4; t += 1024) {
        int cc = t >> 2, r = t & 3;
        lds[cc * 265 + r * 66 + 0]  = 0.f;
        lds[cc * 265 + r * 66 + 65] = 0.f;
    }
    for (int t = tid; t < 32 * 4 * 64; t += 1024) {
        int x = t & 63, r = (t >> 6) & 3, cc = t >> 8;
        int y = 2 * i - 1 + r;
        float v = 0.f;
        if (y >= 0 && y < HH) v = X[(((b * CIN) + (c0 + cc)) * HH + y) * WW + x];
        lds[cc * 265 + r * 66 + 1 + x] = v;
    }
    __syncthreads();

    const int c = tid & 31;
    const int j = tid >> 5;
    const float* base = &lds[c * 265 + 2 * j];

    float t0[4], t1[4], t2[4], t3[4];
#pragma unroll
    for (int y = 0; y < 4; y++) {
        float a  = base[0 * 66 + y];
        float bb = base[1 * 66 + y];
        float cc = base[2 * 66 + y];
        float dd = base[3 * 66 + y];
        t0[y] = a - cc;
        t1[y] = bb + cc;
        t2[y] = cc - bb;
        t3[y] = bb - dd;
    }
    float vm[4][4];
#pragma unroll
    for (int p = 0; p < 4; p++) {
        const float* tp = (p == 0) ? t0 : (p == 1) ? t1 : (p == 2) ? t2 : t3;
        vm[p][0] = tp[0] - tp[2];
        vm[p][1] = tp[1] + tp[2];
        vm[p][2] = tp[2] - tp[1];
        vm[p][3] = tp[1] - tp[3];
    }

    const int bij = b * (TH * TW) + i * TW + j;
    const int vo  = bij * CIN + (c0 + c);
#pragma unroll
    for (int p = 0; p < 4; p++)
#pragma unroll
        for (int q = 0; q < 4; q++)
            V[(size_t)(p * 4 + q) * BPQ + vo] = __float2bfloat16(vm[p][q]);
}

// ---------------------------------------------------------------------------
// Kernel 3: fused GEMM + output transform — R9 SLOT schedule at 2 blocks/CU.
// Block [128 kout x 64 bij], 256 thr = 4 waves (2m x 2n), wave tile 64x32
// (identical per-wave geometry/registers to R9). Grid 512 = 2 blocks/CU:
// co-resident blocks absorb each other's barrier/wait stalls (R9-vs-R13
// experiment: 1 block/CU leaves ~50% idle).
// 32 slots (pq = t>>1, kb = (t&1)*64). LDS 3 bufs x 24KB = 72KB (A 16K+B 8K),
// depth-2 staging (6 gload16/stage), steady vmcnt(6) (stage t+1 landed for
// the kk0 prefetch, stage t+2 in flight), tail 0. lgkm(6)/(6) group split.
// kk0 double-buffered in named sets aX/bX <-> aY/bY; kk1 in a1/b1.
// 6-slot-period chunk loop keeps all mod-3 buffer indices compile-time.
// ---------------------------------------------------------------------------
#define ABYTES 16384
#define BUFSZ  24576

__global__ __launch_bounds__(256, 2) void wg_gemm14(const __hip_bfloat16* __restrict__ U,
                                                    const __hip_bfloat16* __restrict__ V,
                                                    const float* __restrict__ bias,
                                                    float* __restrict__ out) {
    __shared__ char lds[3 * BUFSZ];      // 72 KB

    // bijective XCD swizzle (512 % 8 == 0): 64 consecutive wg per XCD
    int orig = blockIdx.x;
    int wgid = (orig & 7) * 64 + (orig >> 3);
    const int mt = wgid & 1, nt = wgid >> 1;
    const int m0 = mt * 128, n0 = nt * 64;

    const int tid  = threadIdx.x;
    const int lane = tid & 63;
    const int wave = tid >> 6;
    const int wm = wave >> 1, wn = wave & 1;

    // staging: chunk c holds tile granule (row R=c>>3, gran G=(c&7)^(R&7)).
    // A: 1024 chunks (4/thread), B: 512 chunks (2/thread).
    const __hip_bfloat16* pa[4];
    const __hip_bfloat16* pb[2];
    int ldsA[4], ldsB[2];
#pragma unroll
    for (int ch = 0; ch < 4; ch++) {
        int c = ch * 256 + tid;
        int R = c >> 3;
        int G = (c & 7) ^ (R & 7);
        pa[ch] = U + (m0 + R) * CIN + G * 8;
        ldsA[ch] = c * 16;
    }
#pragma unroll
    for (int ch = 0; ch < 2; ch++) {
        int c = ch * 256 + tid;
        int R = c >> 3;
        int G = (c & 7) ^ (R & 7);
        pb[ch] = V + (size_t)(n0 + R) * CIN + G * 8;
        ldsB[ch] = ABYTES + c * 16;
    }

    // ds_read offsets: row r, k-granule g -> byte r*128 + ((g ^ (r&7))<<4)
    const int la = lane & 15, hq = lane >> 4, l7 = lane & 7;
    int aoff[2], boff[2];
#pragma unroll
    for (int kk = 0; kk < 2; kk++) {
        int g = (kk * 4 + hq) ^ l7;
        aoff[kk] = (wm * 64 + la) * 128 + (g << 4);
        boff[kk] = ABYTES + (wn * 32 + la) * 128 + (g << 4);
    }

    f32x4 yac[2][2][4][2];
#pragma unroll
    for (int x = 0; x < 2; x++)
#pragma unroll
        for (int y = 0; y < 2; y++)
#pragma unroll
            for (int mi = 0; mi < 4; mi++)
#pragma unroll
                for (int nj = 0; nj < 2; nj++) yac[x][y][mi][nj] = (f32x4){0.f, 0.f, 0.f, 0.f};
    f32x4 mac[4][2];
    const f32x4 fz = (f32x4){0.f, 0.f, 0.f, 0.f};

    bf16x8 aX[4], bX[2], aY[4], bY[2];   // kk0 double-buffer (named sets)
    bf16x8 a1[4], b1[2];                 // kk1 per-slot set

    auto stage = [&](int s, int sbuf) {
        char* sb = lds + sbuf * BUFSZ;
        const int pq = s >> 1, kb = (s & 1) * 64;
        gload16(pa[0] + pq * APQ + kb, sb + ldsA[0]);
        gload16(pa[1] + pq * APQ + kb, sb + ldsA[1]);
        gload16(pa[2] + pq * APQ + kb, sb + ldsA[2]);
        gload16(pa[3] + pq * APQ + kb, sb + ldsA[3]);
        gload16(pb[0] + (size_t)pq * BPQ + kb, sb + ldsB[0]);
        gload16(pb[1] + (size_t)pq * BPQ + kb, sb + ldsB[1]);
    };

    auto fold = [&](int pq) {            // M[pq] -> Y planes, uniform branches
        const int p = pq >> 2, q = pq & 3;
        const float s1p = (p >= 2) ? -1.f : 1.f;
        const float s1q = (q >= 2) ? -1.f : 1.f;
        if (p != 3 && q != 3) {
#pragma unroll
            for (int mi = 0; mi < 4; mi++)
#pragma unroll
                for (int nj = 0; nj < 2; nj++) yac[0][0][mi][nj] += mac[mi][nj];
        }
        if (p != 3 && q != 0) {
#pragma unroll
            for (int mi = 0; mi < 4; mi++)
#pragma unroll
                for (int nj = 0; nj < 2; nj++) yac[0][1][mi][nj] += s1q * mac[mi][nj];
        }
        if (p != 0 && q != 3) {
#pragma unroll
            for (int mi = 0; mi < 4; mi++)
#pragma unroll
                for (int nj = 0; nj < 2; nj++) yac[1][0][mi][nj] += s1p * mac[mi][nj];
        }
        if (p != 0 && q != 0) {
            const float s11 = s1p * s1q;
#pragma unroll
            for (int mi = 0; mi < 4; mi++)
#pragma unroll
                for (int nj = 0; nj < 2; nj++) yac[1][1][mi][nj] += s11 * mac[mi][nj];
        }
    };

#define SLOT(T, BUF, SBUF, PBUF, AIN, BIN, AOUT, BOUT, VMC, STG, PRE, INIT, LGK2) \
    {                                                                          \
        if (STG) stage((T) + 2, (SBUF));                                       \
        if ((VMC) == 6)      asm volatile("s_waitcnt vmcnt(6)");               \
        else if ((VMC) == 0) asm volatile("s_waitcnt vmcnt(0)");               \
        __builtin_amdgcn_s_barrier();                                          \
        __builtin_amdgcn_sched_barrier(0);                                     \
        {                                                                      \
            const char* rb_ = lds + (BUF) * BUFSZ;                             \
            _Pragma("unroll")                                                  \
            for (int mi = 0; mi < 4; mi++)                                     \
                a1[mi] = *reinterpret_cast<const bf16x8*>(rb_ + aoff[1] + mi * 2048); \
            _Pragma("unroll")                                                  \
            for (int nj = 0; nj < 2; nj++)                                     \
                b1[nj] = *reinterpret_cast<const bf16x8*>(rb_ + boff[1] + nj * 2048); \
        }                                                                      \
        __builtin_amdgcn_sched_barrier(0);                                     \
        asm volatile("s_waitcnt lgkmcnt(6)");                                  \
        __builtin_amdgcn_sched_barrier(0);                                     \
        __builtin_amdgcn_s_setprio(1);                                         \
        _Pragma("unroll")                                                      \
        for (int mi = 0; mi < 4; mi++)                                         \
            _Pragma("unroll")                                                  \
            for (int nj = 0; nj < 2; nj++)                                     \
                mac[mi][nj] = __builtin_amdgcn_mfma_f32_16x16x32_bf16(         \
                    AIN[mi], BIN[nj], (INIT) ? fz : mac[mi][nj], 0, 0, 0);     \
        __builtin_amdgcn_s_setprio(0);                                         \
        if (PRE) {                                                             \
            const char* rb2_ = lds + (PBUF) * BUFSZ;                           \
            _Pragma("unroll")                                                  \
            for (int mi = 0; mi < 4; mi++)                                     \
                AOUT[mi] = *reinterpret_cast<const bf16x8*>(rb2_ + aoff[0] + mi * 2048); \
            _Pragma("unroll")                                                  \
            for (int nj = 0; nj < 2; nj++)                                     \
                BOUT[nj] = *reinterpret_cast<const bf16x8*>(rb2_ + boff[0] + nj * 2048); \
        }                                                                      \
        __builtin_amdgcn_sched_barrier(0);                                     \
        if ((LGK2) == 6) asm volatile("s_waitcnt lgkmcnt(6)");                 \
        else             asm volatile("s_waitcnt lgkmcnt(0)");                 \
        __builtin_amdgcn_sched_barrier(0);                                     \
        __builtin_amdgcn_s_setprio(1);                                         \
        _Pragma("unroll")                                                      \
        for (int mi = 0; mi < 4; mi++)                                         \
            _Pragma("unroll")                                                  \
            for (int nj = 0; nj < 2; nj++)                                     \
                mac[mi][nj] = __builtin_amdgcn_mfma_f32_16x16x32_bf16(         \
                    a1[mi], b1[nj], mac[mi][nj], 0, 0, 0);                     \
        __builtin_amdgcn_s_setprio(0);                                         \
        __builtin_amdgcn_sched_barrier(0);                                     \
        __builtin_amdgcn_s_barrier();                                          \
    }

    // prologue: stages 0,1 in flight; drain stage 0; kk0 regs of buf 0 -> X
    stage(0, 0);
    stage(1, 1);
    asm volatile("s_waitcnt vmcnt(6)");
    __builtin_amdgcn_s_barrier();
    {
        const char* rb_ = lds;
#pragma unroll
        for (int mi = 0; mi < 4; mi++)
            aX[mi] = *reinterpret_cast<const bf16x8*>(rb_ + aoff[0] + mi * 2048);
#pragma unroll
        for (int nj = 0; nj < 2; nj++)
            bX[nj] = *reinterpret_cast<const bf16x8*>(rb_ + boff[0] + nj * 2048);
    }

    // main: 5 chunks x 6 slots (t = 0..29); folds at even t >= 2
    for (int tt = 0; tt < 30; tt += 6) {
        SLOT(tt + 0, 0, 2, 1, aX, bX, aY, bY, 6, true, true, true,  6)
        SLOT(tt + 1, 1, 0, 2, aY, bY, aX, bX, 6, true, true, false, 6)
        fold(tt >> 1);
        SLOT(tt + 2, 2, 1, 0, aX, bX, aY, bY, 6, true, true, true,  6)
        SLOT(tt + 3, 0, 2, 1, aY, bY, aX, bX, 6, true, true, false, 6)
        fold((tt >> 1) + 1);
        SLOT(tt + 4, 1, 0, 2, aX, bX, aY, bY, 6, true, true, true,  6)
        SLOT(tt + 5, 2, 1, 0, aY, bY, aX, bX, 6, true, true, false, 6)
        fold((tt >> 1) + 2);
    }
    // tail: t = 30, 31 (no staging; drain everything before PRE of buf 31)
    SLOT(30, 0, 0, 1, aX, bX, aY, bY, 0, false, true,  true,  6)
    SLOT(31, 1, 0, 0, aY, bY, aX, bX, -1, false, false, false, 0)
    fold(15);

#undef SLOT

    // ---- writeout: D frag: col(bij)=lane&15, row(kout)=(lane>>4)*4+r ----
    const int lr = lane & 15, rg = lane >> 4;
#pragma unroll
    for (int mi = 0; mi < 4; mi++) {
#pragma unroll
        for (int r = 0; r < 4; r++) {
            const int kout = m0 + wm * 64 + mi * 16 + rg * 4 + r;
            const float bvv = bias[kout];
#pragma unroll
            for (int nj = 0; nj < 2; nj++) {
                const int bij = n0 + wn * 32 + nj * 16 + lr;
                const int bb = bij >> 10, ti = (bij >> 5) & 31, tj = bij & 31;
                float* op = out + (((size_t)bb * COUT + kout) * HH + 2 * ti) * WW + 2 * tj;
                *reinterpret_cast<float2*>(op) =
                    make_float2(yac[0][0][mi][nj][r] + bvv, yac[0][1][mi][nj][r] + bvv);
                *reinterpret_cast<float2*>(op + WW) =
                    make_float2(yac[1][0][mi][nj][r] + bvv, yac[1][1][mi][nj][r] + bvv);
            }
        }
    }
}

// ---------------------------------------------------------------------------
extern "C" void kernel_launch(void* const* d_in, const int* in_sizes, int n_in,
                              void* d_out, int out_size, void* d_ws, size_t ws_size,
                              hipStream_t stream) {
    const float* X    = (const float*)d_in[0];
    const float* w    = (const float*)d_in[1];
    const float* bias = (const float*)d_in[2];
    float* out        = (float*)d_out;

    __hip_bfloat16* U = (__hip_bfloat16*)d_ws;                       // 1 MB
    __hip_bfloat16* V = (__hip_bfloat16*)((char*)d_ws + (1u << 20)); // 64 MB

    wg_wtrans<<<(COUT * CIN + 255) / 256, 256, 0, stream>>>(w, U);
    wg_itrans<<<dim3(CIN / 32, TH, BATCH), 1024, 0, stream>>>(X, V);
    wg_gemm14<<<(COUT / 128) * (NT / 64), 256, 0, stream>>>(U, V, bias, out);
}